// Round 5
// baseline (407.726 us; speedup 1.0000x reference)
//
#include <hip/hip_runtime.h>

typedef float v2f __attribute__((ext_vector_type(2)));

#define T_LEN 2048
#define BB    128
#define CC    128
#define EE    32
#define HH    64
#define PRED  336
#define CH    16          // steps per ring chunk
#define NCH   21          // 21*16 = 336

__device__ __forceinline__ v2f mk2(float a, float b) { v2f t; t.x = a; t.y = b; return t; }

// ---------------------------------------------------------------------------
// ONE kernel, one block per batch element, 128 threads (2 waves).
//
// Prologue (both waves): channel-0 extract, 7-tap edge-clamped moving
// average, 4 encoder tanh-GEMVs -> s_v[32]. Then each wave builds its
// per-lane columns of the precomputed matrices IN REGISTERS:
//   M_ag = W_o@[W_in|W_g] (producer), M_r = W_o@Wr (consumer), c-vectors.
//
// Scan: logmap0(expmap0(v)) == v, so the recurrence is Euclidean, and in
// u-space it is linear with constant matrices:
//   A,G state (wave 0):  u_h = silu(A_h)*sigm(G_h);  AG += u@M_ag + c_ag
//   P  state (wave 1):   P  += u@M_r + c_r;  store P   (P_n = pred_n)
// u crosses waves via a chunked double-buffered LDS ring; 2 barriers per
// 16 steps; all reads are wave-broadcast (conflict-free); 4-way FMA trees.
// ---------------------------------------------------------------------------
__global__ __launch_bounds__(128, 1) void fused_kernel(
    const float* __restrict__ x,
    const float* __restrict__ WeT,  const float* __restrict__ beT,
    const float* __restrict__ WeW,  const float* __restrict__ beW,
    const float* __restrict__ WeD,  const float* __restrict__ beD,
    const float* __restrict__ WeR,  const float* __restrict__ beR,
    const float* __restrict__ Wdin, const float* __restrict__ bdin,
    const float* __restrict__ Wdg,  const float* __restrict__ bdg,
    const float* __restrict__ Wdo,  const float* __restrict__ bdo,
    const float* __restrict__ Wr,   const float* __restrict__ br,
    float* __restrict__ out)
{
    __shared__ __align__(16) float s_x   [T_LEN + 6];
    __shared__ __align__(16) float s_tr  [T_LEN];
    __shared__ __align__(16) float s_rs  [T_LEN];
    __shared__ __align__(16) float s_part[4][16][32];
    __shared__ __align__(16) float s_red [4][32];
    __shared__ __align__(16) float s_v   [EE];
    __shared__ __align__(16) float s_u   [2][CH][HH];   // 8 KB ring

    const int tid  = threadIdx.x;
    const int wid  = tid >> 6;
    const int lane = tid & 63;
    const int b    = blockIdx.x;
    const float* xb = x + (size_t)b * T_LEN * CC;

    // ---- channel-0 with halo, edge-clamped
    for (int i = tid; i < T_LEN + 6; i += 128) {
        int t = i - 3;
        t = t < 0 ? 0 : (t > T_LEN - 1 ? T_LEN - 1 : t);
        s_x[i] = xb[(size_t)t * CC];
    }
    __syncthreads();

    // ---- 7-tap moving average (s_x index t+3 == global t)
    for (int t = tid; t < T_LEN; t += 128) {
        float s = 0.f;
        #pragma unroll
        for (int j = 0; j < 7; ++j) s += s_x[t + j];
        float tm = s * (1.0f / 7.0f);
        s_tr[t] = tm;
        s_rs[t] = s_x[t + 3] - tm;
    }
    __syncthreads();

    // ---- 4 encoder GEMV partials: thread = (e-quad, t-group of 128)
    {
        const int eq = tid & 7, tg = tid >> 3;      // eq: e/4, tg: 0..15
        float4 aT = {0,0,0,0}, aW = aT, aD = aT, aR = aT;
        const float4* WT4 = (const float4*)WeT;
        const float4* WW4 = (const float4*)WeW;
        const float4* WD4 = (const float4*)WeD;
        const float4* WR4 = (const float4*)WeR;
        #pragma unroll 4
        for (int j = 0; j < 128; ++j) {
            int t  = tg * 128 + j;
            int wi = t * 8 + eq;
            float trv = s_tr[t], rsv = s_rs[t];
            float4 w;
            w = WT4[wi]; aT.x += trv*w.x; aT.y += trv*w.y; aT.z += trv*w.z; aT.w += trv*w.w;
            w = WW4[wi]; aW.x += rsv*w.x; aW.y += rsv*w.y; aW.z += rsv*w.z; aW.w += rsv*w.w;
            w = WD4[wi]; aD.x += rsv*w.x; aD.y += rsv*w.y; aD.z += rsv*w.z; aD.w += rsv*w.w;
            w = WR4[wi]; aR.x += rsv*w.x; aR.y += rsv*w.y; aR.z += rsv*w.z; aR.w += rsv*w.w;
        }
        ((float4*)&s_part[0][tg][0])[eq] = aT;
        ((float4*)&s_part[1][tg][0])[eq] = aW;
        ((float4*)&s_part[2][tg][0])[eq] = aD;
        ((float4*)&s_part[3][tg][0])[eq] = aR;
    }
    __syncthreads();

    {   // reduce 16 t-groups for each (matrix, e)
        const int m = tid >> 5, e = tid & 31;
        float s = 0.f;
        #pragma unroll
        for (int g = 0; g < 16; ++g) s += s_part[m][g][e];
        s_red[m][e] = s;
    }
    __syncthreads();

    if (tid < EE) {
        s_v[tid] = tanhf(s_red[0][tid] + beT[tid])
                 + tanhf(s_red[1][tid] + beW[tid])
                 + tanhf(s_red[2][tid] + beD[tid])
                 + tanhf(s_red[3][tid] + beR[tid]);
    }
    __syncthreads();

    if (wid == 0) {
        // ================= producer: A,G state for h = lane =================
        v2f wig[EE];                       // {W_in[e][lane], W_g[e][lane]}
        #pragma unroll
        for (int e = 0; e < EE; ++e)
            wig[e] = mk2(Wdin[e * HH + lane], Wdg[e * HH + lane]);

        v2f m_ag[HH];                      // M_ag[k][lane] = sum_e Wo[k,e]*wig[e]
        #pragma unroll 2
        for (int k = 0; k < HH; ++k) {
            v2f m = mk2(0.f, 0.f);
            #pragma unroll
            for (int e = 0; e < EE; ++e) m += Wdo[k * EE + e] * wig[e];
            m_ag[k] = m;
        }
        v2f c_ag = mk2(0.f, 0.f);
        v2f ag   = mk2(bdin[lane], bdg[lane]);
        #pragma unroll
        for (int e = 0; e < EE; ++e) {
            c_ag += bdo[e]  * wig[e];
            ag   += s_v[e]  * wig[e];
        }

        for (int c = 0; c < NCH + 1; ++c) {
            if (c < NCH) {
                float* ring = &s_u[c & 1][0][0];
                #pragma unroll 2
                for (int i = 0; i < CH; ++i) {
                    float a = ag.x, g = ag.y;
                    float u = a * __builtin_amdgcn_rcpf(
                        (1.f + __expf(-a)) * (1.f + __expf(-g)));
                    ring[i * HH + lane] = u;     // DS in-order: read-back safe
                    v2f acc0 = c_ag, acc1 = mk2(0.f,0.f),
                        acc2 = acc1, acc3 = acc1;
                    const float4* u4 = (const float4*)(ring + i * HH);
                    #pragma unroll
                    for (int k = 0; k < HH / 4; ++k) {
                        float4 q = u4[k];
                        acc0 += q.x * m_ag[4 * k    ];
                        acc1 += q.y * m_ag[4 * k + 1];
                        acc2 += q.z * m_ag[4 * k + 2];
                        acc3 += q.w * m_ag[4 * k + 3];
                    }
                    ag += (acc0 + acc1) + (acc2 + acc3);
                }
            }
            __syncthreads();
        }
    } else {
        // ============ consumer: P state (pred) for c = 2*lane,2*lane+1 =====
        v2f wr2[EE];                       // Wr[e][2*lane .. 2*lane+1]
        #pragma unroll
        for (int e = 0; e < EE; ++e)
            wr2[e] = *(const v2f*)(Wr + e * CC + 2 * lane);

        v2f m_r[HH];                       // M_r[k][2lane..] = sum_e Wo[k,e]*wr2[e]
        #pragma unroll 2
        for (int k = 0; k < HH; ++k) {
            v2f m = mk2(0.f, 0.f);
            #pragma unroll
            for (int e = 0; e < EE; ++e) m += Wdo[k * EE + e] * wr2[e];
            m_r[k] = m;
        }
        v2f c_r = mk2(0.f, 0.f);
        v2f P   = *(const v2f*)(br + 2 * lane);
        #pragma unroll
        for (int e = 0; e < EE; ++e) {
            c_r += bdo[e] * wr2[e];
            P   += s_v[e] * wr2[e];        // P_{-1} = tv0@Wr + br
        }

        float* outb = out + (size_t)b * PRED * CC + 2 * lane;

        for (int c = 0; c < NCH + 1; ++c) {
            if (c > 0) {
                const float* ring = &s_u[(c - 1) & 1][0][0];
                const int n0 = (c - 1) * CH;
                #pragma unroll 2
                for (int i = 0; i < CH; ++i) {
                    v2f acc0 = c_r, acc1 = mk2(0.f,0.f),
                        acc2 = acc1, acc3 = acc1;
                    const float4* u4 = (const float4*)(ring + i * HH);
                    #pragma unroll
                    for (int k = 0; k < HH / 4; ++k) {
                        float4 q = u4[k];
                        acc0 += q.x * m_r[4 * k    ];
                        acc1 += q.y * m_r[4 * k + 1];
                        acc2 += q.z * m_r[4 * k + 2];
                        acc3 += q.w * m_r[4 * k + 3];
                    }
                    P += (acc0 + acc1) + (acc2 + acc3);
                    *(v2f*)(outb + (size_t)(n0 + i) * CC) = P;
                }
            }
            __syncthreads();
        }
    }
}

extern "C" void kernel_launch(void* const* d_in, const int* in_sizes, int n_in,
                              void* d_out, int out_size, void* d_ws, size_t ws_size,
                              hipStream_t stream)
{
    const float* x    = (const float*)d_in[0];
    const float* WeT  = (const float*)d_in[1];
    const float* beT  = (const float*)d_in[2];
    const float* WeW  = (const float*)d_in[3];
    const float* beW  = (const float*)d_in[4];
    const float* WeD  = (const float*)d_in[5];
    const float* beD  = (const float*)d_in[6];
    const float* WeR  = (const float*)d_in[7];
    const float* beR  = (const float*)d_in[8];
    const float* Wdin = (const float*)d_in[9];
    const float* bdin = (const float*)d_in[10];
    const float* Wdg  = (const float*)d_in[11];
    const float* bdg  = (const float*)d_in[12];
    const float* Wdo  = (const float*)d_in[13];
    const float* bdo  = (const float*)d_in[14];
    const float* Wr   = (const float*)d_in[15];
    const float* br   = (const float*)d_in[16];

    fused_kernel<<<BB, 128, 0, stream>>>(x, WeT, beT, WeW, beW, WeD, beD,
                                         WeR, beR, Wdin, bdin, Wdg, bdg,
                                         Wdo, bdo, Wr, br, (float*)d_out);
}